// Round 3
// baseline (6123.145 us; speedup 1.0000x reference)
//
#include <hip/hip_runtime.h>
#include <stdint.h>

#define BDIM 64
#define TDIM 512
#define EDIM 512
#define HDIM 512

typedef __attribute__((ext_vector_type(8))) short bf16x8;
typedef __attribute__((ext_vector_type(4))) float f32x4;
typedef __attribute__((ext_vector_type(4))) unsigned int u32x4;
typedef __attribute__((ext_vector_type(4))) unsigned short u16x4;
typedef unsigned long long u64t;

static __device__ __forceinline__ unsigned short f2bf(float f) {
  union { float f; uint32_t u; } c; c.f = f;
  uint32_t u = c.u;
  uint32_t r = u + 0x7fffu + ((u >> 16) & 1u);
  return (unsigned short)(r >> 16);
}
static __device__ __forceinline__ float bf2f(unsigned short s) {
  union { uint32_t u; float f; } c; c.u = ((uint32_t)s) << 16;
  return c.f;
}

// float -> OCP e4m3fn (RNE, saturate to 448)
static __device__ __forceinline__ unsigned char f2e4m3(float f) {
  uint32_t u = __float_as_uint(f);
  unsigned char s = (unsigned char)((u >> 31) << 7);
  float a = fabsf(f);
  if (a >= 448.f) return (unsigned char)(s | 0x7e);
  if (a < 0.015625f) {               // denormal region: grid 2^-9
    int q = (int)rintf(a * 512.f);   // 0..8
    if (q >= 8) return (unsigned char)(s | 0x08);
    return (unsigned char)(s | q);
  }
  int e; frexpf(a, &e);
  int E = e - 1;
  int q = (int)rintf(ldexpf(a, 3 - E));  // 8..16
  if (q == 16) { q = 8; E++; }
  int exp8 = E + 7;
  if (exp8 >= 16) return (unsigned char)(s | 0x7e);
  return (unsigned char)(s | (exp8 << 3) | (q & 7));
}

// swizzle for 1KB-row tiles (512 bf16 per row)
#define SWZ(row, byteInRow) ((((row)*1024) + (byteInRow)) ^ ((((row)&7))<<4))
// swizzle for 128B-row tiles (64 bf16 per row)
#define SWZA(row, byteInRow) ((((row)*128) + (byteInRow)) ^ ((((row)&7))<<4))

// ---------------- small utility kernels ----------------

__global__ void sentinel_kern(float* out, int n) {
  for (int i = blockIdx.x * blockDim.x + threadIdx.x; i < n; i += gridDim.x * blockDim.x)
    out[i] = -12345.0f;
}

__global__ void conv_w(const float* __restrict__ Wz, const float* __restrict__ Wr,
                       const float* __restrict__ Wh,
                       unsigned short* __restrict__ Wxb, unsigned short* __restrict__ Whb,
                       unsigned char* __restrict__ Wr8) {
  int idx = blockIdx.x * 256 + threadIdx.x;
  if (idx >= 3 * 512 * 1024) return;
  int g = idx >> 19;
  int rem = idx & 524287;
  int j = rem >> 10, k = rem & 1023;
  const float* W = (g == 0) ? Wz : (g == 1) ? Wr : Wh;
  float v = W[(size_t)j * 1024 + k];
  unsigned short b = f2bf(v);
  if (k < 512) Wxb[((size_t)g * 512 + j) * 512 + k] = b;
  else {
    Whb[((size_t)g * 512 + j) * 512 + (k - 512)] = b;
    if (g == 1) Wr8[(size_t)j * 512 + (k - 512)] = f2e4m3(v * 16.f);
  }
}

__global__ void conv_x(const float* __restrict__ x, unsigned short* __restrict__ xb, int n4) {
  for (int i = blockIdx.x * blockDim.x + threadIdx.x; i < n4; i += gridDim.x * blockDim.x) {
    f32x4 v = ((const f32x4*)x)[i];
    u16x4 o;
    o[0] = f2bf(v[0]); o[1] = f2bf(v[1]); o[2] = f2bf(v[2]); o[3] = f2bf(v[3]);
    ((u16x4*)xb)[i] = o;
  }
}

__global__ void add_out(float* __restrict__ out, const float* __restrict__ Hb, int n4) {
  for (int i = blockIdx.x * blockDim.x + threadIdx.x; i < n4; i += gridDim.x * blockDim.x) {
    f32x4 a = ((const f32x4*)out)[i];
    f32x4 b = ((const f32x4*)Hb)[i];
    ((f32x4*)out)[i] = a + b;
  }
}

// ---------------- phase A: G = x @ Wx^T + bias (bf16 out) ----------------
// M = B*T = 32768 (row m = b*T+t), N = 1536 (n = gate*512 + j), K = 512

__global__ __launch_bounds__(256, 2)
void gru_xproj(const unsigned short* __restrict__ xb,
               const unsigned short* __restrict__ Wxb,
               const float* __restrict__ bz, const float* __restrict__ br,
               const float* __restrict__ bh,
               unsigned short* __restrict__ Gb) {
  __shared__ __align__(16) unsigned short lA[128 * 64];
  __shared__ __align__(16) unsigned short lB[128 * 64];
  const int tid = threadIdx.x;
  const int m0 = blockIdx.x * 128;
  const int n0 = blockIdx.y * 128;
  const int w = tid >> 6, lane = tid & 63, cl = lane & 15, q = lane >> 4;
  const int wr = w >> 1, wc = w & 1;
  f32x4 acc[4][4];
#pragma unroll
  for (int i = 0; i < 4; i++)
#pragma unroll
    for (int j = 0; j < 4; j++) acc[i][j] = (f32x4){0.f, 0.f, 0.f, 0.f};

  for (int ko = 0; ko < 8; ko++) {
    int k0 = ko * 64;
#pragma unroll
    for (int cc = 0; cc < 4; cc++) {
      int qq = tid * 4 + cc;
      int row = qq >> 3, kc = qq & 7;
      u32x4 va = *(const u32x4*)(xb + ((size_t)(m0 + row) * EDIM + k0 + kc * 8));
      *(u32x4*)((char*)lA + SWZA(row, kc * 16)) = va;
      u32x4 vb = *(const u32x4*)(Wxb + ((size_t)(n0 + row) * EDIM + k0 + kc * 8));
      *(u32x4*)((char*)lB + SWZA(row, kc * 16)) = vb;
    }
    __syncthreads();
#pragma unroll
    for (int ks = 0; ks < 2; ks++) {
      bf16x8 af[4], bfv[4];
#pragma unroll
      for (int i = 0; i < 4; i++) {
        int rl = wr * 64 + i * 16 + cl;
        af[i] = *(const bf16x8*)((char*)lA + SWZA(rl, ks * 64 + q * 16));
      }
#pragma unroll
      for (int j = 0; j < 4; j++) {
        int rl = wc * 64 + j * 16 + cl;
        bfv[j] = *(const bf16x8*)((char*)lB + SWZA(rl, ks * 64 + q * 16));
      }
#pragma unroll
      for (int i = 0; i < 4; i++)
#pragma unroll
        for (int j = 0; j < 4; j++)
          acc[i][j] = __builtin_amdgcn_mfma_f32_16x16x32_bf16(af[i], bfv[j], acc[i][j], 0, 0, 0);
    }
    __syncthreads();
  }
  const int g = n0 >> 9;
  const float* bias = (g == 0) ? bz : (g == 1) ? br : bh;
#pragma unroll
  for (int i = 0; i < 4; i++) {
#pragma unroll
    for (int j = 0; j < 4; j++) {
      int n = n0 + wc * 64 + j * 16 + cl;
      float bv = bias[n & 511];
#pragma unroll
      for (int ii = 0; ii < 4; ii++) {
        int m = m0 + wr * 64 + i * 16 + q * 4 + ii;
        Gb[(size_t)m * 1536 + n] = f2bf(acc[i][j][ii] + bv);
      }
    }
  }
}

// ---------------- persistent recurrence: ONE exchange per step ----------------
// 128 wgs: gid = bid&7 -> group (dir = gid>>2, bg = gid&3); cg = bid>>3 -> own cols j0=cg*32.
// Per wg: 16 batches x 32 own h-cols. r-gate replicated per-wg via fp8 Wr_h in VGPRs
// (wave w owns r-cols w*128..+127). z and h~ in bf16 from LDS weight tiles.
// Cross-wg: publish own-col h(t) (bf16 + fp8, parity double-buffered) via relaxed
// agent atomics; per-wg flag; single-wave poll. No mid-step exchange.

__global__ __launch_bounds__(256, 1)
void gru_persist(const unsigned short* __restrict__ Gb,
                 const float* __restrict__ h0,
                 unsigned short* __restrict__ Hstb,   // [2][2*64][512] bf16
                 unsigned char*  __restrict__ Hst8,   // [2][2*64][512] fp8 (x16)
                 unsigned int*   __restrict__ flags,  // [8][16]
                 float* __restrict__ outp,
                 float* __restrict__ Hb,
                 const unsigned short* __restrict__ Whb,
                 const unsigned char*  __restrict__ Wr8) {
  __shared__ __align__(16) unsigned short lw_z[32 * 512];  // 32KB own-col z weights
  __shared__ __align__(16) unsigned short lw_h[32 * 512];  // 32KB own-col h~ weights
  __shared__ __align__(16) unsigned short lhb[16 * 512];   // 16KB staged h (bf16, SWZ)
  __shared__ __align__(16) unsigned short lrh[16 * 512];   // 16KB r*h (bf16, SWZ)
  __shared__ __align__(16) unsigned short lgr[16 * 512];   // 16KB G_r slice (plain)
  __shared__ __align__(16) unsigned short lgz[16 * 32];    // 1KB
  __shared__ __align__(16) unsigned short lgh[16 * 32];    // 1KB
  __shared__ float lz[16 * 32];                            // 2KB
  __shared__ float lhp[16 * 32];                           // 2KB own-col h (fp32)
  __shared__ unsigned char lpk8[16 * 32];                  // 512B fp8 pack

  const int tid = threadIdx.x;
  const int bid = blockIdx.x;
  const int gid = bid & 7;
  const int cg = bid >> 3;
  const int dir = gid >> 2;
  const int bg = gid & 3;
  const int j0 = cg * 32;
  const int w = tid >> 6;
  const int lane = tid & 63;
  const int c = lane & 15;
  const int q = lane >> 4;
  const int rj0 = w * 128;
  const int HHALF = 2 * 64 * 512;
  unsigned int* fbase = flags + gid * 16;

  // ---- one-time: weight LDS tiles (z gate0, h~ gate2) ----
  {
    int col = tid >> 3, ch = tid & 7;
#pragma unroll
    for (int u = 0; u < 8; u++) {
      u32x4 vz = *(const u32x4*)(Whb + (((size_t)0 * 512 + j0 + col) * 512) + ch * 64 + u * 8);
      *(u32x4*)((char*)lw_z + SWZ(col, ch * 128 + u * 16)) = vz;
      u32x4 vh = *(const u32x4*)(Whb + (((size_t)2 * 512 + j0 + col) * 512) + ch * 64 + u * 8);
      *(u32x4*)((char*)lw_h + SWZ(col, ch * 128 + u * 16)) = vh;
    }
  }
  // ---- one-time: Wr fp8 fragments into VGPRs (wave's 128 r-cols) ----
  u64t wrg[8][16];
  {
    const u64t* wsrc = (const u64t*)Wr8;
#pragma unroll
    for (int ct = 0; ct < 8; ct++)
#pragma unroll
      for (int ks = 0; ks < 16; ks++)
        wrg[ct][ks] = wsrc[(size_t)(rj0 + ct * 16 + c) * 64 + ks * 4 + q];
  }
  // ---- init own-col h from h0; publish h_0 into parity-0 buffers ----
  {
    int e0 = tid * 2;
    int row = e0 >> 5, jl = e0 & 31;
    int b = bg * 16 + row;
    float v0 = h0[(size_t)b * HDIM + j0 + jl];
    float v1 = h0[(size_t)b * HDIM + j0 + jl + 1];
    lhp[row * 32 + jl] = v0;
    lhp[row * 32 + jl + 1] = v1;
    lpk8[row * 32 + jl] = f2e4m3(v0 * 16.f);
    lpk8[row * 32 + jl + 1] = f2e4m3(v1 * 16.f);
    size_t hb_i = (size_t)(dir * 64 + b) * 512 + j0 + jl;
    __hip_atomic_store(&Hstb[hb_i], f2bf(v0), __ATOMIC_RELAXED, __HIP_MEMORY_SCOPE_AGENT);
    __hip_atomic_store(&Hstb[hb_i + 1], f2bf(v1), __ATOMIC_RELAXED, __HIP_MEMORY_SCOPE_AGENT);
  }
  __syncthreads();
  if (tid < 128) {
    int row = tid >> 3, ch = tid & 7;
    unsigned int pv = *(unsigned int*)&lpk8[row * 32 + ch * 4];
    __hip_atomic_store((unsigned int*)(Hst8 + (size_t)(dir * 64 + bg * 16 + row) * 512 + j0) + ch,
                       pv, __ATOMIC_RELAXED, __HIP_MEMORY_SCOPE_AGENT);
  }
  asm volatile("s_waitcnt vmcnt(0)" ::: "memory");
  __syncthreads();
  if (tid == 0)
    __hip_atomic_store(&fbase[cg], 1u, __ATOMIC_RELAXED, __HIP_MEMORY_SCOPE_AGENT);

  const float inv256 = 1.f / 256.f;

  for (int s = 1; s <= TDIM; s++) {
    int t = dir ? (TDIM - s) : (s - 1);
    const unsigned short* Hstb_r = Hstb + (size_t)((s - 1) & 1) * HHALF;
    const unsigned char*  Hst8_r = Hst8 + (size_t)((s - 1) & 1) * HHALF;
    unsigned short* Hstb_w = Hstb + (size_t)(s & 1) * HHALF;
    unsigned char*  Hst8_w = Hst8 + (size_t)(s & 1) * HHALF;

    // ---- G prefetch (plain cached loads) + LDS write, all BEFORE the poll ----
    {
      int row = tid >> 4, lr = tid & 15;
      size_t m = (size_t)(bg * 16 + row) * TDIM + t;
      const u32x4* gsrc = (const u32x4*)(Gb + m * 1536 + 512 + lr * 32);
      u32x4 g0 = gsrc[0], g1 = gsrc[1], g2 = gsrc[2], g3 = gsrc[3];
      int e0 = tid * 2;
      int zr = e0 >> 5, zl = e0 & 31;
      size_t mz = (size_t)(bg * 16 + zr) * TDIM + t;
      unsigned int gz = *(const unsigned int*)(Gb + mz * 1536 + j0 + zl);
      unsigned int gh = *(const unsigned int*)(Gb + mz * 1536 + 1024 + j0 + zl);
      u32x4* ld = (u32x4*)((char*)lgr + row * 1024 + lr * 64);
      ld[0] = g0; ld[1] = g1; ld[2] = g2; ld[3] = g3;
      *(unsigned int*)((char*)lgz + zr * 64 + zl * 2) = gz;
      *(unsigned int*)((char*)lgh + zr * 64 + zl * 2) = gh;
    }

    // ---- wait: all 16 wgs of group published h_{s-1} ----
    if (w == 0) {
      unsigned tgt = (unsigned)s;
      while (true) {
        unsigned fv = __hip_atomic_load(&fbase[lane & 15], __ATOMIC_RELAXED, __HIP_MEMORY_SCOPE_AGENT);
        if (__all(fv >= tgt)) break;
      }
    }
    __syncthreads();

    // ---- direct-global fp8 A-fragments (h_{s-1}, rows = batches) ----
    u64t af8[16];
    {
      const u64t* hsrc = (const u64t*)Hst8_r + (size_t)(dir * 64 + bg * 16 + c) * 64 + q;
#pragma unroll
      for (int ks = 0; ks < 16; ks++)
        af8[ks] = __hip_atomic_load(hsrc + ks * 4, __ATOMIC_RELAXED, __HIP_MEMORY_SCOPE_AGENT);
    }
    // ---- stage h_{s-1} bf16 into LDS (SWZ) ----
    {
      int row = tid & 15;
      int cb = (tid >> 4) * 64;
      const u64t* src = (const u64t*)((const char*)Hstb_r +
                        ((size_t)(dir * 64 + bg * 16 + row) * 512) * 2 + cb);
      u64t v[8];
#pragma unroll
      for (int i = 0; i < 8; i++)
        v[i] = __hip_atomic_load(&src[i], __ATOMIC_RELAXED, __HIP_MEMORY_SCOPE_AGENT);
      char* dst = (char*)lhb;
#pragma unroll
      for (int i = 0; i < 8; i++)
        *(u64t*)(dst + SWZ(row, cb + i * 8)) = v[i];
    }
    __syncthreads();

    // ---- r-matmul: 8 col-tiles x K=512, fp8, weights from VGPRs ----
    f32x4 racc[8];
#pragma unroll
    for (int ct = 0; ct < 8; ct++) racc[ct] = (f32x4){0.f, 0.f, 0.f, 0.f};
#pragma unroll
    for (int ks = 0; ks < 16; ks++)
#pragma unroll
      for (int ct = 0; ct < 8; ct++)
        racc[ct] = __builtin_amdgcn_mfma_f32_16x16x32_fp8_fp8(
            (long)af8[ks], (long)wrg[ct][ks], racc[ct], 0, 0, 0);

    // ---- z-matmul (waves 0,1): bf16, own cols ----
    if (w < 2) {
      f32x4 zacc = (f32x4){0.f, 0.f, 0.f, 0.f};
#pragma unroll
      for (int ks = 0; ks < 16; ks++) {
        bf16x8 azf = *(const bf16x8*)((char*)lhb + SWZ(c, ks * 64 + q * 16));
        bf16x8 bzf = *(const bf16x8*)((char*)lw_z + SWZ(w * 16 + c, ks * 64 + q * 16));
        zacc = __builtin_amdgcn_mfma_f32_16x16x32_bf16(azf, bzf, zacc, 0, 0, 0);
      }
#pragma unroll
      for (int i = 0; i < 4; i++) {
        int row = q * 4 + i, zl = w * 16 + c;
        float gz = bf2f(*(const unsigned short*)((char*)lgz + row * 64 + zl * 2));
        float pre = zacc[i] + gz;
        pre = fminf(fmaxf(pre, -30.f), 30.f);
        lz[row * 32 + zl] = 1.f / (1.f + __expf(-pre));
      }
    }

    // ---- r pointwise + r*h into LDS (all waves, own 128 r-cols) ----
#pragma unroll
    for (int ct = 0; ct < 8; ct++) {
      int j = rj0 + ct * 16 + c;
#pragma unroll
      for (int i = 0; i < 4; i++) {
        int row = q * 4 + i;
        float gr = bf2f(*(const unsigned short*)((char*)lgr + row * 1024 + j * 2));
        float pre = racc[ct][i] * inv256 + gr;
        pre = fminf(fmaxf(pre, -30.f), 30.f);
        float r = 1.f / (1.f + __expf(-pre));
        float hb = bf2f(*(const unsigned short*)((char*)lhb + SWZ(row, j * 2)));
        *(unsigned short*)((char*)lrh + SWZ(row, j * 2)) = f2bf(r * hb);
      }
    }
    __syncthreads();   // lrh + lz ready

    // ---- h~ matmul + blend + publish (waves 2,3) ----
    if (w >= 2) {
      int hsub = w - 2;
      f32x4 hacc = (f32x4){0.f, 0.f, 0.f, 0.f};
#pragma unroll
      for (int ks = 0; ks < 16; ks++) {
        bf16x8 arf = *(const bf16x8*)((char*)lrh + SWZ(c, ks * 64 + q * 16));
        bf16x8 bhf = *(const bf16x8*)((char*)lw_h + SWZ(hsub * 16 + c, ks * 64 + q * 16));
        hacc = __builtin_amdgcn_mfma_f32_16x16x32_bf16(arf, bhf, hacc, 0, 0, 0);
      }
      float* op = dir ? Hb : outp;
#pragma unroll
      for (int i = 0; i < 4; i++) {
        int row = q * 4 + i, hl = hsub * 16 + c;
        int b = bg * 16 + row, j = j0 + hl;
        float gh = bf2f(*(const unsigned short*)((char*)lgh + row * 64 + hl * 2));
        float pre = hacc[i] + gh;
        pre = fminf(fmaxf(pre, -15.f), 15.f);
        float e2 = __expf(2.f * pre);
        float th = (e2 - 1.f) / (e2 + 1.f);
        float hp = lhp[row * 32 + hl];
        float z = lz[row * 32 + hl];
        float hn = hp + z * (th - hp);
        op[((size_t)b * TDIM + t) * HDIM + j] = hn;
        __hip_atomic_store(&Hstb_w[(size_t)(dir * 64 + b) * 512 + j], f2bf(hn),
                           __ATOMIC_RELAXED, __HIP_MEMORY_SCOPE_AGENT);
        lhp[row * 32 + hl] = hn;
        lpk8[row * 32 + hl] = f2e4m3(hn * 16.f);
      }
    }
    __syncthreads();   // lpk8 ready
    if (tid < 128) {
      int row = tid >> 3, ch = tid & 7;
      unsigned int pv = *(unsigned int*)&lpk8[row * 32 + ch * 4];
      __hip_atomic_store((unsigned int*)(Hst8_w + (size_t)(dir * 64 + bg * 16 + row) * 512 + j0) + ch,
                         pv, __ATOMIC_RELAXED, __HIP_MEMORY_SCOPE_AGENT);
    }
    asm volatile("s_waitcnt vmcnt(0)" ::: "memory");
    __syncthreads();
    if (tid == 0)
      __hip_atomic_store(&fbase[cg], (unsigned)(s + 1), __ATOMIC_RELAXED, __HIP_MEMORY_SCOPE_AGENT);
  }
}

// ---------------- host ----------------

extern "C" void kernel_launch(void* const* d_in, const int* in_sizes, int n_in,
                              void* d_out, int out_size, void* d_ws, size_t ws_size,
                              hipStream_t stream) {
  (void)in_sizes; (void)n_in;
  const float* x  = (const float*)d_in[0];
  const float* h0 = (const float*)d_in[1];
  const float* Wz = (const float*)d_in[2];
  const float* bz = (const float*)d_in[3];
  const float* Wr = (const float*)d_in[4];
  const float* br = (const float*)d_in[5];
  const float* Wh = (const float*)d_in[6];
  const float* bh = (const float*)d_in[7];
  float* outp = (float*)d_out;

  const size_t szG    = (size_t)32768 * 1536 * 2;       // bf16 G
  const size_t szXb   = (size_t)BDIM * TDIM * EDIM * 2;
  const size_t szW    = (size_t)3 * 512 * 512 * 2;
  const size_t szWr8  = (size_t)512 * 512;
  const size_t szHb   = (size_t)BDIM * TDIM * HDIM * 4;
  const size_t szHstb = (size_t)2 * 2 * 64 * 512 * 2;
  const size_t szHst8 = (size_t)2 * 2 * 64 * 512;
  const size_t fixed  = szXb + 2 * szW + szWr8 + szHb + szHstb + szHst8 + 16384;

  if (ws_size < fixed + szG) {
    sentinel_kern<<<256, 256, 0, stream>>>(outp, out_size);
    return;
  }

  size_t off = 0;
  char* base = (char*)d_ws;
  auto alloc = [&](size_t sz) { char* p = base + off; off = (off + sz + 255) & ~(size_t)255; return p; };
  unsigned short* Gb   = (unsigned short*)alloc(szG);
  unsigned short* xb   = (unsigned short*)alloc(szXb);
  unsigned short* Wxb  = (unsigned short*)alloc(szW);
  unsigned short* Whb  = (unsigned short*)alloc(szW);
  unsigned char*  Wr8  = (unsigned char*)alloc(szWr8);
  float*          Hbuf = (float*)alloc(szHb);
  unsigned short* Hstb = (unsigned short*)alloc(szHstb);
  unsigned char*  Hst8 = (unsigned char*)alloc(szHst8);
  unsigned int*   flags= (unsigned int*)alloc(4096);

  hipMemsetAsync(flags, 0, 4096, stream);
  conv_w<<<(3 * 512 * 1024 + 255) / 256, 256, 0, stream>>>(Wz, Wr, Wh, Wxb, Whb, Wr8);
  conv_x<<<2048, 256, 0, stream>>>(x, xb, (BDIM * TDIM * EDIM) / 4);
  gru_xproj<<<dim3(256, 12), 256, 0, stream>>>(xb, Wxb, bz, br, bh, Gb);
  gru_persist<<<128, 256, 0, stream>>>(Gb, h0, Hstb, Hst8, flags, outp, Hbuf, Whb, Wr8);
  add_out<<<2048, 256, 0, stream>>>(outp, Hbuf, (BDIM * TDIM * HDIM) / 4);
  hipMemcpyAsync(outp + (size_t)BDIM * TDIM * HDIM, h0,
                 (size_t)BDIM * HDIM * sizeof(float), hipMemcpyDeviceToDevice, stream);
}

// Round 4
// 4846.650 us; speedup vs baseline: 1.2634x; 1.2634x over previous
//
#include <hip/hip_runtime.h>
#include <stdint.h>

#define BDIM 64
#define TDIM 512
#define EDIM 512
#define HDIM 512

typedef __attribute__((ext_vector_type(8))) short bf16x8;
typedef __attribute__((ext_vector_type(4))) float f32x4;
typedef __attribute__((ext_vector_type(4))) unsigned int u32x4;
typedef __attribute__((ext_vector_type(4))) unsigned short u16x4;
typedef unsigned long long u64t;

static __device__ __forceinline__ unsigned short f2bf(float f) {
  union { float f; uint32_t u; } c; c.f = f;
  uint32_t u = c.u;
  uint32_t r = u + 0x7fffu + ((u >> 16) & 1u);
  return (unsigned short)(r >> 16);
}
static __device__ __forceinline__ float bf2f(unsigned short s) {
  union { uint32_t u; float f; } c; c.u = ((uint32_t)s) << 16;
  return c.f;
}

// float -> OCP e4m3fn (RNE, saturate) — host-side weight conversion only
static __device__ __forceinline__ unsigned char f2e4m3(float f) {
  uint32_t u = __float_as_uint(f);
  unsigned char s = (unsigned char)((u >> 31) << 7);
  float a = fabsf(f);
  if (a >= 448.f) return (unsigned char)(s | 0x7e);
  if (a < 0.015625f) {
    int q = (int)rintf(a * 512.f);
    if (q >= 8) return (unsigned char)(s | 0x08);
    return (unsigned char)(s | q);
  }
  int e; frexpf(a, &e);
  int E = e - 1;
  int q = (int)rintf(ldexpf(a, 3 - E));
  if (q == 16) { q = 8; E++; }
  int exp8 = E + 7;
  if (exp8 >= 16) return (unsigned char)(s | 0x7e);
  return (unsigned char)(s | (exp8 << 3) | (q & 7));
}

// swizzle for 1KB-row tiles (512 bf16 per row)
#define SWZ(row, byteInRow) ((((row)*1024) + (byteInRow)) ^ ((((row)&7))<<4))
// swizzle for 128B-row tiles (64 bf16 per row)
#define SWZA(row, byteInRow) ((((row)*128) + (byteInRow)) ^ ((((row)&7))<<4))

// fp8 shadow row stride (bytes): 528 = 512 + 16 to spread rows across banks
#define H8S 528

// ---------------- small utility kernels ----------------

__global__ void sentinel_kern(float* out, int n) {
  for (int i = blockIdx.x * blockDim.x + threadIdx.x; i < n; i += gridDim.x * blockDim.x)
    out[i] = -12345.0f;
}

__global__ void conv_w(const float* __restrict__ Wz, const float* __restrict__ Wr,
                       const float* __restrict__ Wh,
                       unsigned short* __restrict__ Wxb, unsigned short* __restrict__ Whb,
                       unsigned char* __restrict__ Wr8) {
  int idx = blockIdx.x * 256 + threadIdx.x;
  if (idx >= 3 * 512 * 1024) return;
  int g = idx >> 19;
  int rem = idx & 524287;
  int j = rem >> 10, k = rem & 1023;
  const float* W = (g == 0) ? Wz : (g == 1) ? Wr : Wh;
  float v = W[(size_t)j * 1024 + k];
  unsigned short b = f2bf(v);
  if (k < 512) Wxb[((size_t)g * 512 + j) * 512 + k] = b;
  else {
    Whb[((size_t)g * 512 + j) * 512 + (k - 512)] = b;
    if (g == 1) Wr8[(size_t)j * 512 + (k - 512)] = f2e4m3(v * 16.f);
  }
}

__global__ void conv_x(const float* __restrict__ x, unsigned short* __restrict__ xb, int n4) {
  for (int i = blockIdx.x * blockDim.x + threadIdx.x; i < n4; i += gridDim.x * blockDim.x) {
    f32x4 v = ((const f32x4*)x)[i];
    u16x4 o;
    o[0] = f2bf(v[0]); o[1] = f2bf(v[1]); o[2] = f2bf(v[2]); o[3] = f2bf(v[3]);
    ((u16x4*)xb)[i] = o;
  }
}

__global__ void add_out(float* __restrict__ out, const float* __restrict__ Hb, int n4) {
  for (int i = blockIdx.x * blockDim.x + threadIdx.x; i < n4; i += gridDim.x * blockDim.x) {
    f32x4 a = ((const f32x4*)out)[i];
    f32x4 b = ((const f32x4*)Hb)[i];
    ((f32x4*)out)[i] = a + b;
  }
}

// ---------------- phase A: G = x @ Wx^T + bias (bf16 out) ----------------

__global__ __launch_bounds__(256, 2)
void gru_xproj(const unsigned short* __restrict__ xb,
               const unsigned short* __restrict__ Wxb,
               const float* __restrict__ bz, const float* __restrict__ br,
               const float* __restrict__ bh,
               unsigned short* __restrict__ Gb) {
  __shared__ __align__(16) unsigned short lA[128 * 64];
  __shared__ __align__(16) unsigned short lB[128 * 64];
  const int tid = threadIdx.x;
  const int m0 = blockIdx.x * 128;
  const int n0 = blockIdx.y * 128;
  const int w = tid >> 6, lane = tid & 63, cl = lane & 15, q = lane >> 4;
  const int wr = w >> 1, wc = w & 1;
  f32x4 acc[4][4];
#pragma unroll
  for (int i = 0; i < 4; i++)
#pragma unroll
    for (int j = 0; j < 4; j++) acc[i][j] = (f32x4){0.f, 0.f, 0.f, 0.f};

  for (int ko = 0; ko < 8; ko++) {
    int k0 = ko * 64;
#pragma unroll
    for (int cc = 0; cc < 4; cc++) {
      int qq = tid * 4 + cc;
      int row = qq >> 3, kc = qq & 7;
      u32x4 va = *(const u32x4*)(xb + ((size_t)(m0 + row) * EDIM + k0 + kc * 8));
      *(u32x4*)((char*)lA + SWZA(row, kc * 16)) = va;
      u32x4 vb = *(const u32x4*)(Wxb + ((size_t)(n0 + row) * EDIM + k0 + kc * 8));
      *(u32x4*)((char*)lB + SWZA(row, kc * 16)) = vb;
    }
    __syncthreads();
#pragma unroll
    for (int ks = 0; ks < 2; ks++) {
      bf16x8 af[4], bfv[4];
#pragma unroll
      for (int i = 0; i < 4; i++) {
        int rl = wr * 64 + i * 16 + cl;
        af[i] = *(const bf16x8*)((char*)lA + SWZA(rl, ks * 64 + q * 16));
      }
#pragma unroll
      for (int j = 0; j < 4; j++) {
        int rl = wc * 64 + j * 16 + cl;
        bfv[j] = *(const bf16x8*)((char*)lB + SWZA(rl, ks * 64 + q * 16));
      }
#pragma unroll
      for (int i = 0; i < 4; i++)
#pragma unroll
        for (int j = 0; j < 4; j++)
          acc[i][j] = __builtin_amdgcn_mfma_f32_16x16x32_bf16(af[i], bfv[j], acc[i][j], 0, 0, 0);
    }
    __syncthreads();
  }
  const int g = n0 >> 9;
  const float* bias = (g == 0) ? bz : (g == 1) ? br : bh;
#pragma unroll
  for (int i = 0; i < 4; i++) {
#pragma unroll
    for (int j = 0; j < 4; j++) {
      int n = n0 + wc * 64 + j * 16 + cl;
      float bv = bias[n & 511];
#pragma unroll
      for (int ii = 0; ii < 4; ii++) {
        int m = m0 + wr * 64 + i * 16 + q * 4 + ii;
        Gb[(size_t)m * 1536 + n] = f2bf(acc[i][j][ii] + bv);
      }
    }
  }
}

// ---------------- persistent recurrence: ONE exchange/step, low-contention sync ----
// 128 wgs: gid = bid&7 (dir = gid>>2, bg = gid&3); cg = bid>>3, own cols j0=cg*32.
// Flags: one 128B line per (gid, cg). Publish = 1 plain flag store; poll = wave 0,
// lanes 0-15 on distinct lines, s_sleep backoff. fp8 A-fragments built in-LDS from
// staged bf16 h via v_cvt_pk_fp8_f32 (no second global stream).

__global__ __launch_bounds__(256, 1)
void gru_persist(const unsigned short* __restrict__ Gb,
                 const float* __restrict__ h0,
                 unsigned short* __restrict__ Hstb,   // [2][2*64][512] bf16
                 unsigned int*   __restrict__ flags,  // [8][16] x 128B lines
                 float* __restrict__ outp,
                 float* __restrict__ Hb,
                 const unsigned short* __restrict__ Whb,
                 const unsigned char*  __restrict__ Wr8) {
  __shared__ __align__(16) unsigned short lw_z[32 * 512];  // 32KB
  __shared__ __align__(16) unsigned short lw_h[32 * 512];  // 32KB
  __shared__ __align__(16) unsigned short lhb[16 * 512];   // 16KB staged h bf16 (SWZ)
  __shared__ __align__(16) unsigned short lrh[16 * 512];   // 16KB r*h bf16 (SWZ)
  __shared__ __align__(16) unsigned short lgr[16 * 512];   // 16KB G_r slice
  __shared__ __align__(16) unsigned char  lh8[16 * H8S];   // 8.25KB fp8 shadow of h
  __shared__ __align__(16) unsigned short lgz[16 * 32];
  __shared__ __align__(16) unsigned short lgh[16 * 32];
  __shared__ float lz[16 * 32];
  __shared__ float lhp[16 * 32];

  const int tid = threadIdx.x;
  const int bid = blockIdx.x;
  const int gid = bid & 7;
  const int cg = bid >> 3;
  const int dir = gid >> 2;
  const int bg = gid & 3;
  const int j0 = cg * 32;
  const int w = tid >> 6;
  const int lane = tid & 63;
  const int c = lane & 15;
  const int q = lane >> 4;
  const int rj0 = w * 128;
  const int HHALF = 2 * 64 * 512;
  unsigned int* fown = flags + (gid * 16 + cg) * 32;
  unsigned int* fpoll = flags + (gid * 16 + (lane & 15)) * 32;

  // ---- one-time: weight LDS tiles (z gate0, h~ gate2) ----
  {
    int col = tid >> 3, ch = tid & 7;
#pragma unroll
    for (int u = 0; u < 8; u++) {
      u32x4 vz = *(const u32x4*)(Whb + (((size_t)0 * 512 + j0 + col) * 512) + ch * 64 + u * 8);
      *(u32x4*)((char*)lw_z + SWZ(col, ch * 128 + u * 16)) = vz;
      u32x4 vh = *(const u32x4*)(Whb + (((size_t)2 * 512 + j0 + col) * 512) + ch * 64 + u * 8);
      *(u32x4*)((char*)lw_h + SWZ(col, ch * 128 + u * 16)) = vh;
    }
  }
  // ---- one-time: Wr fp8 fragments into VGPRs (wave's 128 r-cols) ----
  u64t wrg[8][16];
  {
    const u64t* wsrc = (const u64t*)Wr8;
#pragma unroll
    for (int ct = 0; ct < 8; ct++)
#pragma unroll
      for (int ks = 0; ks < 16; ks++)
        wrg[ct][ks] = wsrc[(size_t)(rj0 + ct * 16 + c) * 64 + ks * 4 + q];
  }
  // ---- init own-col h from h0; publish into parity-0 buffer ----
  {
    int e0 = tid * 2;
    int row = e0 >> 5, jl = e0 & 31;
    int b = bg * 16 + row;
    float v0 = h0[(size_t)b * HDIM + j0 + jl];
    float v1 = h0[(size_t)b * HDIM + j0 + jl + 1];
    lhp[row * 32 + jl] = v0;
    lhp[row * 32 + jl + 1] = v1;
    unsigned int pk = (unsigned int)f2bf(v0) | ((unsigned int)f2bf(v1) << 16);
    __hip_atomic_store((unsigned int*)&Hstb[(size_t)(dir * 64 + b) * 512 + j0 + jl], pk,
                       __ATOMIC_RELAXED, __HIP_MEMORY_SCOPE_AGENT);
  }
  asm volatile("s_waitcnt vmcnt(0)" ::: "memory");
  __syncthreads();
  if (tid == 0)
    __hip_atomic_store(fown, 1u, __ATOMIC_RELAXED, __HIP_MEMORY_SCOPE_AGENT);

  const float inv256 = 1.f / 256.f;

  for (int s = 1; s <= TDIM; s++) {
    int t = dir ? (TDIM - s) : (s - 1);
    const unsigned short* Hstb_r = Hstb + (size_t)((s - 1) & 1) * HHALF;
    unsigned short* Hstb_w = Hstb + (size_t)(s & 1) * HHALF;

    // ---- G prefetch (independent of the rendezvous) ----
    {
      int row = tid >> 4, lr = tid & 15;
      size_t m = (size_t)(bg * 16 + row) * TDIM + t;
      const u32x4* gsrc = (const u32x4*)(Gb + m * 1536 + 512 + lr * 32);
      u32x4 g0 = gsrc[0], g1 = gsrc[1], g2 = gsrc[2], g3 = gsrc[3];
      int e0 = tid * 2;
      int zr = e0 >> 5, zl = e0 & 31;
      size_t mz = (size_t)(bg * 16 + zr) * TDIM + t;
      unsigned int gz = *(const unsigned int*)(Gb + mz * 1536 + j0 + zl);
      unsigned int gh = *(const unsigned int*)(Gb + mz * 1536 + 1024 + j0 + zl);
      u32x4* ld = (u32x4*)((char*)lgr + row * 1024 + lr * 64);
      ld[0] = g0; ld[1] = g1; ld[2] = g2; ld[3] = g3;
      *(unsigned int*)((char*)lgz + zr * 64 + zl * 2) = gz;
      *(unsigned int*)((char*)lgh + zr * 64 + zl * 2) = gh;
    }

    // ---- rendezvous: wave 0, lanes 0-15 poll 16 distinct 128B lines ----
    if (w == 0) {
      unsigned tgt = (unsigned)s;
      while (true) {
        unsigned fv = tgt;
        if (lane < 16)
          fv = __hip_atomic_load(fpoll, __ATOMIC_RELAXED, __HIP_MEMORY_SCOPE_AGENT);
        if (__all(fv >= tgt)) break;
        __builtin_amdgcn_s_sleep(2);
      }
    }
    __syncthreads();

    // ---- stage h_{s-1}: bf16 -> lhb (SWZ) and fp8 shadow -> lh8 ----
    {
      int row = tid & 15;
      int cb = (tid >> 4) * 64;   // 64 bytes = 32 bf16 cols starting at cb/2
      const u64t* src = (const u64t*)((const char*)Hstb_r +
                        ((size_t)(dir * 64 + bg * 16 + row) * 512) * 2 + cb);
      u64t v[8];
#pragma unroll
      for (int i = 0; i < 8; i++)
        v[i] = __hip_atomic_load(&src[i], __ATOMIC_RELAXED, __HIP_MEMORY_SCOPE_AGENT);
      char* dst = (char*)lhb;
#pragma unroll
      for (int i = 0; i < 8; i++)
        *(u64t*)(dst + SWZ(row, cb + i * 8)) = v[i];
      // fp8 shadow: 32 bf16 -> 32 fp8 (x16 scale), HW converter
      unsigned int pk8[8];
#pragma unroll
      for (int i = 0; i < 8; i++) {
        const unsigned short* sp = (const unsigned short*)&v[i];
        float f0 = bf2f(sp[0]) * 16.f, f1 = bf2f(sp[1]) * 16.f;
        float f2 = bf2f(sp[2]) * 16.f, f3 = bf2f(sp[3]) * 16.f;
        int d = 0;
        d = __builtin_amdgcn_cvt_pk_fp8_f32(f0, f1, d, false);
        d = __builtin_amdgcn_cvt_pk_fp8_f32(f2, f3, d, true);
        pk8[i] = (unsigned int)d;
      }
      u32x4* h8d = (u32x4*)(lh8 + row * H8S + cb / 2);
      h8d[0] = (u32x4){pk8[0], pk8[1], pk8[2], pk8[3]};
      h8d[1] = (u32x4){pk8[4], pk8[5], pk8[6], pk8[7]};
    }
    __syncthreads();

    // ---- fp8 A-fragments from LDS shadow ----
    u64t af8[16];
#pragma unroll
    for (int ks = 0; ks < 16; ks++)
      af8[ks] = *(const u64t*)(lh8 + c * H8S + ks * 32 + q * 8);

    // ---- r-matmul: 8 col-tiles x K=512, fp8, weights resident in VGPRs ----
    f32x4 racc[8];
#pragma unroll
    for (int ct = 0; ct < 8; ct++) racc[ct] = (f32x4){0.f, 0.f, 0.f, 0.f};
#pragma unroll
    for (int ks = 0; ks < 16; ks++)
#pragma unroll
      for (int ct = 0; ct < 8; ct++)
        racc[ct] = __builtin_amdgcn_mfma_f32_16x16x32_fp8_fp8(
            (long)af8[ks], (long)wrg[ct][ks], racc[ct], 0, 0, 0);

    // ---- z-matmul (waves 0,1): bf16, own cols ----
    if (w < 2) {
      f32x4 zacc = (f32x4){0.f, 0.f, 0.f, 0.f};
#pragma unroll
      for (int ks = 0; ks < 16; ks++) {
        bf16x8 azf = *(const bf16x8*)((char*)lhb + SWZ(c, ks * 64 + q * 16));
        bf16x8 bzf = *(const bf16x8*)((char*)lw_z + SWZ(w * 16 + c, ks * 64 + q * 16));
        zacc = __builtin_amdgcn_mfma_f32_16x16x32_bf16(azf, bzf, zacc, 0, 0, 0);
      }
#pragma unroll
      for (int i = 0; i < 4; i++) {
        int row = q * 4 + i, zl = w * 16 + c;
        float gz = bf2f(*(const unsigned short*)((char*)lgz + row * 64 + zl * 2));
        float pre = zacc[i] + gz;
        pre = fminf(fmaxf(pre, -30.f), 30.f);
        lz[row * 32 + zl] = 1.f / (1.f + __expf(-pre));
      }
    }

    // ---- r pointwise + r*h into LDS (all waves, own 128 r-cols) ----
#pragma unroll
    for (int ct = 0; ct < 8; ct++) {
      int j = rj0 + ct * 16 + c;
#pragma unroll
      for (int i = 0; i < 4; i++) {
        int row = q * 4 + i;
        float gr = bf2f(*(const unsigned short*)((char*)lgr + row * 1024 + j * 2));
        float pre = racc[ct][i] * inv256 + gr;
        pre = fminf(fmaxf(pre, -30.f), 30.f);
        float r = 1.f / (1.f + __expf(-pre));
        float hb = bf2f(*(const unsigned short*)((char*)lhb + SWZ(row, j * 2)));
        *(unsigned short*)((char*)lrh + SWZ(row, j * 2)) = f2bf(r * hb);
      }
    }
    __syncthreads();   // lrh + lz ready

    // ---- h~ matmul + blend (waves 2,3) ----
    if (w >= 2) {
      int hsub = w - 2;
      f32x4 hacc = (f32x4){0.f, 0.f, 0.f, 0.f};
#pragma unroll
      for (int ks = 0; ks < 16; ks++) {
        bf16x8 arf = *(const bf16x8*)((char*)lrh + SWZ(c, ks * 64 + q * 16));
        bf16x8 bhf = *(const bf16x8*)((char*)lw_h + SWZ(hsub * 16 + c, ks * 64 + q * 16));
        hacc = __builtin_amdgcn_mfma_f32_16x16x32_bf16(arf, bhf, hacc, 0, 0, 0);
      }
      float* op = dir ? Hb : outp;
#pragma unroll
      for (int i = 0; i < 4; i++) {
        int row = q * 4 + i, hl = hsub * 16 + c;
        int b = bg * 16 + row, j = j0 + hl;
        float gh = bf2f(*(const unsigned short*)((char*)lgh + row * 64 + hl * 2));
        float pre = hacc[i] + gh;
        pre = fminf(fmaxf(pre, -15.f), 15.f);
        float e2 = __expf(2.f * pre);
        float th = (e2 - 1.f) / (e2 + 1.f);
        float hp = lhp[row * 32 + hl];
        float z = lz[row * 32 + hl];
        float hn = hp + z * (th - hp);
        op[((size_t)b * TDIM + t) * HDIM + j] = hn;
        lhp[row * 32 + hl] = hn;
      }
    }
    __syncthreads();   // lhp(t) ready

    // ---- publish h(t): packed u32 stores from lhp by all 256 threads ----
    {
      int row = tid >> 4, jl2 = (tid & 15) * 2;
      float v0 = lhp[row * 32 + jl2];
      float v1 = lhp[row * 32 + jl2 + 1];
      unsigned int pk = (unsigned int)f2bf(v0) | ((unsigned int)f2bf(v1) << 16);
      __hip_atomic_store(
          (unsigned int*)&Hstb_w[(size_t)(dir * 64 + bg * 16 + row) * 512 + j0 + jl2],
          pk, __ATOMIC_RELAXED, __HIP_MEMORY_SCOPE_AGENT);
    }
    asm volatile("s_waitcnt vmcnt(0)" ::: "memory");
    __syncthreads();
    if (tid == 0)
      __hip_atomic_store(fown, (unsigned)(s + 1), __ATOMIC_RELAXED, __HIP_MEMORY_SCOPE_AGENT);
  }
}

// ---------------- host ----------------

extern "C" void kernel_launch(void* const* d_in, const int* in_sizes, int n_in,
                              void* d_out, int out_size, void* d_ws, size_t ws_size,
                              hipStream_t stream) {
  (void)in_sizes; (void)n_in;
  const float* x  = (const float*)d_in[0];
  const float* h0 = (const float*)d_in[1];
  const float* Wz = (const float*)d_in[2];
  const float* bz = (const float*)d_in[3];
  const float* Wr = (const float*)d_in[4];
  const float* br = (const float*)d_in[5];
  const float* Wh = (const float*)d_in[6];
  const float* bh = (const float*)d_in[7];
  float* outp = (float*)d_out;

  const size_t szG    = (size_t)32768 * 1536 * 2;       // bf16 G
  const size_t szXb   = (size_t)BDIM * TDIM * EDIM * 2;
  const size_t szW    = (size_t)3 * 512 * 512 * 2;
  const size_t szWr8  = (size_t)512 * 512;
  const size_t szHb   = (size_t)BDIM * TDIM * HDIM * 4;
  const size_t szHstb = (size_t)2 * 2 * 64 * 512 * 2;
  const size_t szFl   = 16384;
  const size_t fixed  = szXb + 2 * szW + szWr8 + szHb + szHstb + szFl + 16384;

  if (ws_size < fixed + szG) {
    sentinel_kern<<<256, 256, 0, stream>>>(outp, out_size);
    return;
  }

  size_t off = 0;
  char* base = (char*)d_ws;
  auto alloc = [&](size_t sz) { char* p = base + off; off = (off + sz + 255) & ~(size_t)255; return p; };
  unsigned short* Gb   = (unsigned short*)alloc(szG);
  unsigned short* xb   = (unsigned short*)alloc(szXb);
  unsigned short* Wxb  = (unsigned short*)alloc(szW);
  unsigned short* Whb  = (unsigned short*)alloc(szW);
  unsigned char*  Wr8  = (unsigned char*)alloc(szWr8);
  float*          Hbuf = (float*)alloc(szHb);
  unsigned short* Hstb = (unsigned short*)alloc(szHstb);
  unsigned int*   flags= (unsigned int*)alloc(szFl);

  hipMemsetAsync(flags, 0, szFl, stream);
  conv_w<<<(3 * 512 * 1024 + 255) / 256, 256, 0, stream>>>(Wz, Wr, Wh, Wxb, Whb, Wr8);
  conv_x<<<2048, 256, 0, stream>>>(x, xb, (BDIM * TDIM * EDIM) / 4);
  gru_xproj<<<dim3(256, 12), 256, 0, stream>>>(xb, Wxb, bz, br, bh, Gb);
  gru_persist<<<128, 256, 0, stream>>>(Gb, h0, Hstb, flags, outp, Hbuf, Whb, Wr8);
  add_out<<<2048, 256, 0, stream>>>(outp, Hbuf, (BDIM * TDIM * HDIM) / 4);
  hipMemcpyAsync(outp + (size_t)BDIM * TDIM * HDIM, h0,
                 (size_t)BDIM * HDIM * sizeof(float), hipMemcpyDeviceToDevice, stream);
}